// Round 6
// baseline (134.737 us; speedup 1.0000x reference)
//
#include <hip/hip_runtime.h>
#include <hip/hip_bf16.h>

#define BATCH 512
#define PIX   65536
#define NOUT  512
#define COUT  4
#define NCLS  10

#define NH    2                   // pixel halves (xT buffer reused -> ws ~34MB)
#define HPIX  (PIX / NH)          // 32768 pixels per half
#define HBITS 15                  // bits for p_local in key

__device__ __forceinline__ unsigned short f2bf(float f) {
    __hip_bfloat16 h = __float2bfloat16(f);      // RNE
    return *reinterpret_cast<unsigned short*>(&h);
}

// ---------------------------------------------------------------------------
// A: per-half bin histogram (counts zeroed beforehand)
// ---------------------------------------------------------------------------
__global__ __launch_bounds__(256) void hist_kernel(
    const int* __restrict__ seg, int* __restrict__ counts)
{
    const int p = blockIdx.x * 256 + threadIdx.x;
    atomicAdd(&counts[(p >> HBITS) * NOUT + seg[p]], 1);
}

// ---------------------------------------------------------------------------
// B: exclusive prefix per half -> cursor
// ---------------------------------------------------------------------------
__global__ __launch_bounds__(512) void prefix_kernel(
    const int* __restrict__ counts, int* __restrict__ cursor)
{
    __shared__ int sc[NOUT];
    const int q = blockIdx.x, t = threadIdx.x;
    const int v = counts[q * NOUT + t];
    sc[t] = v;
    __syncthreads();
    for (int off = 1; off < NOUT; off <<= 1) {
        const int u = (t >= off) ? sc[t - off] : 0;
        __syncthreads();
        sc[t] += u;
        __syncthreads();
    }
    cursor[q * NOUT + t] = sc[t] - v;
}

// ---------------------------------------------------------------------------
// C: scatter into bin-sorted rank order (direct rank slot; scalar walk later)
// key = (bin << 15) | p_local
// ---------------------------------------------------------------------------
__global__ __launch_bounds__(256) void scatter_kernel(
    const int* __restrict__ seg, int* __restrict__ cursor,
    unsigned* __restrict__ key)
{
    const int p  = blockIdx.x * 256 + threadIdx.x;
    const int sl = p >> HBITS;
    const int b  = seg[p];
    const int r  = atomicAdd(&cursor[sl * NOUT + b], 1);
    key[(size_t)sl * HPIX + r] = ((unsigned)b << HBITS) | (unsigned)(p & (HPIX - 1));
}

// ---------------------------------------------------------------------------
// D: Weff[j,k] = sum_c W_fgl[c,j]*W_fc[(c*NOUT+j)*NCLS+k]; also init
//    out[n,k] = cst[k] (cst = bias term folded; out finished by out_kernel).
// ---------------------------------------------------------------------------
__global__ __launch_bounds__(512) void weff_kernel(
    const float* __restrict__ W_fgl, const float* __restrict__ b_fgl,
    const float* __restrict__ W_fc,  const float* __restrict__ b_fc,
    float* __restrict__ Weff, float* __restrict__ out)
{
    const int j = threadIdx.x;

    float wf[COUT], bf[COUT];
#pragma unroll
    for (int c = 0; c < COUT; ++c) {
        wf[c] = W_fgl[c * NOUT + j];
        bf[c] = b_fgl[c * NOUT + j];
    }

    float cpart[NCLS];
#pragma unroll
    for (int k = 0; k < NCLS; ++k) {
        float w = 0.f, cb = 0.f;
#pragma unroll
        for (int c = 0; c < COUT; ++c) {
            const float wfc = W_fc[(c * NOUT + j) * NCLS + k];
            w  += wf[c] * wfc;
            cb += bf[c] * wfc;
        }
        Weff[j * NCLS + k] = w;
        cpart[k] = cb;
    }

#pragma unroll
    for (int k = 0; k < NCLS; ++k)
#pragma unroll
        for (int off = 32; off; off >>= 1)
            cpart[k] += __shfl_down(cpart[k], off);

    __shared__ float red[8 * NCLS];
    __shared__ float cs[NCLS];
    if ((j & 63) == 0) {
#pragma unroll
        for (int k = 0; k < NCLS; ++k) red[(j >> 6) * NCLS + k] = cpart[k];
    }
    __syncthreads();
    if (j < NCLS) {
        float s = b_fc[j];
#pragma unroll
        for (int w = 0; w < 8; ++w) s += red[w * NCLS + j];
        cs[j] = s;
    }
    __syncthreads();
    for (int i = j; i < BATCH * NCLS; i += 512) out[i] = cs[i % NCLS];
}

// ---------------------------------------------------------------------------
// T: transpose+convert one half: xT[p_local][n] (bf16) from x[n][p] (f32).
// Tile 64 rows x 256 pixels via LDS. Reads coalesced 1KB/instr; writes
// 16B/lane contiguous per pixel row.
// ---------------------------------------------------------------------------
__global__ __launch_bounds__(256) void transpose_kernel(
    const float* __restrict__ x, unsigned short* __restrict__ xTh, int half)
{
    __shared__ unsigned short T[256][68];    // pad 68 -> 4-way worst conflicts
    const int t   = threadIdx.x;
    const int pw  = blockIdx.x;              // 0..127 pixel window
    const int rg  = blockIdx.y;              // 0..7 row group
    const int n0  = rg * 64;
    const int gp0 = half * HPIX + pw * 256;  // global pixel base

#pragma unroll
    for (int i = 0; i < 16; ++i) {
        const int f  = i * 256 + t;
        const int r  = f >> 6;               // 0..63
        const int c4 = f & 63;               // float4 column
        const float4 v = *reinterpret_cast<const float4*>(
            x + (size_t)(n0 + r) * PIX + gp0 + c4 * 4);
        T[c4 * 4 + 0][r] = f2bf(v.x);
        T[c4 * 4 + 1][r] = f2bf(v.y);
        T[c4 * 4 + 2][r] = f2bf(v.z);
        T[c4 * 4 + 3][r] = f2bf(v.w);
    }
    __syncthreads();

    // thread t owns pixel pw*256+t: write 64 rows = 128B contiguous
    uint4* dst = reinterpret_cast<uint4*>(
        xTh + (size_t)(pw * 256 + t) * BATCH + n0);
#pragma unroll
    for (int jj = 0; jj < 8; ++jj) {
        const uint2 a = *reinterpret_cast<const uint2*>(&T[t][8 * jj]);
        const uint2 b = *reinterpret_cast<const uint2*>(&T[t][8 * jj + 4]);
        dst[jj] = make_uint4(a.x, a.y, b.x, b.y);
    }
}

// ---------------------------------------------------------------------------
// S: segment sum over one half. Wave = 64 rows (lanes), 64 sorted ranks,
// scalar key walk (readlane -> uniform branch), coalesced 128B xT loads,
// register run accumulation, rare coalesced wave-wide atomic flush.
// hT zeroed beforehand.
// ---------------------------------------------------------------------------
__global__ __launch_bounds__(256) void segsum_kernel(
    const unsigned short* __restrict__ xTh, const unsigned* __restrict__ keyh,
    float* __restrict__ hT)
{
    const int t    = threadIdx.x;
    const int w    = t >> 6;
    const int lane = t & 63;
    const int wid  = blockIdx.x * 4 + w;     // 0..4095
    const int sg   = wid & 511;              // rank segment
    const int rg   = wid >> 9;               // row group
    const int n    = rg * 64 + lane;

    const unsigned kv = keyh[sg * 64 + lane];   // 64 keys, one per lane

    int   prev = __builtin_amdgcn_readlane((int)kv, 0) >> HBITS;
    float acc  = 0.f;
#pragma unroll
    for (int i = 0; i < 64; ++i) {
        const int ki = __builtin_amdgcn_readlane((int)kv, i);  // scalar
        const int b  = ki >> HBITS;
        const int p  = ki & (HPIX - 1);
        if (b != prev) {                     // uniform branch
            unsafeAtomicAdd(&hT[(size_t)prev * BATCH + n], acc);
            acc  = 0.f;
            prev = b;
        }
        acc += __uint_as_float((unsigned)xTh[(size_t)p * BATCH + n] << 16);
    }
    unsafeAtomicAdd(&hT[(size_t)prev * BATCH + n], acc);
}

// ---------------------------------------------------------------------------
// F: out[n,k] += sum_{j in chunk} hT[j][n] * Weff[j,k]   (out pre-init = cst)
// grid 16: blockIdx&1 = row half, blockIdx>>1 = j-chunk of 64
// ---------------------------------------------------------------------------
__global__ __launch_bounds__(256) void out_kernel(
    const float* __restrict__ hT, const float* __restrict__ Weff,
    float* __restrict__ out)
{
    __shared__ float wl[64 * NCLS];
    const int t  = threadIdx.x;
    const int jc = blockIdx.x >> 1;
    for (int i = t; i < 64 * NCLS; i += 256) wl[i] = Weff[jc * 64 * NCLS + i];
    __syncthreads();

    const int n = (blockIdx.x & 1) * 256 + t;   // 256 rows per block
    float acc[NCLS] = {};
#pragma unroll
    for (int jj = 0; jj < 64; ++jj) {
        const float hv = hT[(size_t)(jc * 64 + jj) * BATCH + n];
#pragma unroll
        for (int k = 0; k < NCLS; ++k) acc[k] += hv * wl[jj * NCLS + k];
    }
#pragma unroll
    for (int k = 0; k < NCLS; ++k)
        unsafeAtomicAdd(&out[n * NCLS + k], acc[k]);
}

// ---------------------------------------------------------------------------
extern "C" void kernel_launch(void* const* d_in, const int* in_sizes, int n_in,
                              void* d_out, int out_size, void* d_ws, size_t ws_size,
                              hipStream_t stream)
{
    const float* x     = (const float*)d_in[0];
    const float* W_fgl = (const float*)d_in[1];
    const float* b_fgl = (const float*)d_in[2];
    const float* W_fc  = (const float*)d_in[3];
    const float* b_fc  = (const float*)d_in[4];
    const int*   seg   = (const int*)d_in[5];
    float*       out   = (float*)d_out;

    // ws: hT 1MB | counts 4KB | cursor 4KB | Weff 20KB | key 256KB | xT 32MB
    char* ws = (char*)d_ws;
    const size_t hT_b   = (size_t)NOUT * BATCH * sizeof(float);   // 1 MiB
    const size_t cnt_b  = (size_t)NH * NOUT * sizeof(int);        // 4 KiB
    const size_t weff_b = (size_t)NOUT * NCLS * sizeof(float);    // 20 KiB
    const size_t key_b  = (size_t)PIX * sizeof(unsigned);         // 256 KiB

    float*          hT     = (float*)ws;
    int*            counts = (int*)(ws + hT_b);
    int*            cursor = (int*)(ws + hT_b + cnt_b);
    float*          Weff   = (float*)(ws + hT_b + 2 * cnt_b);
    unsigned*       key    = (unsigned*)(ws + hT_b + 2 * cnt_b + weff_b);
    unsigned short* xT     = (unsigned short*)(ws + hT_b + 2 * cnt_b + weff_b + key_b);

    hipMemsetAsync(d_ws, 0, hT_b + cnt_b, stream);   // zero hT + counts

    hist_kernel   <<<dim3(PIX / 256), 256, 0, stream>>>(seg, counts);
    prefix_kernel <<<dim3(NH),        512, 0, stream>>>(counts, cursor);
    scatter_kernel<<<dim3(PIX / 256), 256, 0, stream>>>(seg, cursor, key);

    weff_kernel   <<<dim3(1),         512, 0, stream>>>(W_fgl, b_fgl, W_fc, b_fc,
                                                        Weff, out);

    for (int h = 0; h < NH; ++h) {
        transpose_kernel<<<dim3(HPIX / 256, BATCH / 64), 256, 0, stream>>>(x, xT, h);
        segsum_kernel   <<<dim3(1024), 256, 0, stream>>>(xT, key + (size_t)h * HPIX, hT);
    }

    out_kernel<<<dim3(16), 256, 0, stream>>>(hT, Weff, out);
}

// Round 7
// 82.237 us; speedup vs baseline: 1.6384x; 1.6384x over previous
//
#include <hip/hip_runtime.h>
#include <hip/hip_bf16.h>

#define BATCH 512
#define PIX   65536
#define NOUT  512
#define COUT  4
#define NCLS  10

#define TP_BLOCKS 2048            // 256 pixel-windows x 8 row-groups
#define H_BLOCKS  64              // hist blocks (1024 px each)
#define Z_BLOCKS  32              // zero-hT blocks

__device__ __forceinline__ unsigned f2bf2(float a, float b) {
    __hip_bfloat16 ha = __float2bfloat16(a), hb = __float2bfloat16(b);
    return (unsigned)*(unsigned short*)&ha | ((unsigned)*(unsigned short*)&hb << 16);
}

// ---------------------------------------------------------------------------
// 1: transpose (x f32 -> xT bf16 [p][n]) || private-slab hist || zero hT ||
//    weff+out-init. One dispatch, disjoint outputs, no pre-zeroed globals.
// ---------------------------------------------------------------------------
__global__ __launch_bounds__(256) void fused1_kernel(
    const float* __restrict__ x, const int* __restrict__ seg,
    const float* __restrict__ W_fgl, const float* __restrict__ b_fgl,
    const float* __restrict__ W_fc,  const float* __restrict__ b_fc,
    unsigned short* __restrict__ xT, int* __restrict__ slab,
    float* __restrict__ hT, float* __restrict__ Weff, float* __restrict__ out)
{
    __shared__ __align__(16) unsigned char smem[64 * 258 * 2];  // 33 KB
    const int bid = blockIdx.x, t = threadIdx.x;

    if (bid < TP_BLOCKS) {
        // ---------- transpose 64 rows x 256 pixels ----------
        unsigned short (*T)[258] = (unsigned short (*)[258])smem;
        const int pw = bid & 255, rg = bid >> 8;
        const int w = t >> 6, l = t & 63;
#pragma unroll
        for (int i = 0; i < 16; ++i) {
            const int row = i * 4 + w;                       // wave-uniform
            const float4 v = *(const float4*)(
                x + (size_t)(rg * 64 + row) * PIX + pw * 256 + l * 4);
            // lane-stride 8B LDS writes -> conflict-free
            *(unsigned*)&T[row][l * 4]     = f2bf2(v.x, v.y);
            *(unsigned*)&T[row][l * 4 + 2] = f2bf2(v.z, v.w);
        }
        __syncthreads();
        const int q = t & 7;                                 // 16B chunk id
#pragma unroll
        for (int cw = 0; cw < 8; ++cw) {
            const int p = cw * 32 + (t >> 3);                // pixel 0..255
            const unsigned r0 = (unsigned)T[q*8+0][p] | ((unsigned)T[q*8+1][p] << 16);
            const unsigned r1 = (unsigned)T[q*8+2][p] | ((unsigned)T[q*8+3][p] << 16);
            const unsigned r2 = (unsigned)T[q*8+4][p] | ((unsigned)T[q*8+5][p] << 16);
            const unsigned r3 = (unsigned)T[q*8+6][p] | ((unsigned)T[q*8+7][p] << 16);
            // wave writes 8 pixels x 128B contiguous chunks
            *(uint4*)(xT + (size_t)(pw * 256 + p) * BATCH + rg * 64 + q * 8) =
                make_uint4(r0, r1, r2, r3);
        }
    } else if (bid < TP_BLOCKS + H_BLOCKS) {
        // ---------- private-slab histogram: 1024 px, 16 LDS-atomic instrs ----------
        int* lcnt = (int*)smem;
        const int hb = bid - TP_BLOCKS;
        lcnt[t] = 0; lcnt[t + 256] = 0;
        __syncthreads();
#pragma unroll
        for (int i = 0; i < 4; ++i)
            atomicAdd(&lcnt[seg[hb * 1024 + i * 256 + t]], 1);
        __syncthreads();
        slab[hb * NOUT + t]       = lcnt[t];
        slab[hb * NOUT + t + 256] = lcnt[t + 256];
    } else if (bid < TP_BLOCKS + H_BLOCKS + Z_BLOCKS) {
        // ---------- zero hT (1 MiB) ----------
        const int zb = bid - TP_BLOCKS - H_BLOCKS;
        float4* dst = (float4*)hT + (size_t)zb * 2048;
        const float4 z = make_float4(0.f, 0.f, 0.f, 0.f);
#pragma unroll
        for (int i = 0; i < 8; ++i) dst[i * 256 + t] = z;
    } else {
        // ---------- weff + out init (cst) ----------
        float* red = (float*)smem;            // 4 waves * NCLS
        float* cs  = red + 4 * NCLS;
        float cpart[NCLS];
#pragma unroll
        for (int k = 0; k < NCLS; ++k) cpart[k] = 0.f;
#pragma unroll
        for (int jj = 0; jj < 2; ++jj) {
            const int j = jj * 256 + t;
            float wf[COUT], bf[COUT];
#pragma unroll
            for (int c = 0; c < COUT; ++c) {
                wf[c] = W_fgl[c * NOUT + j];
                bf[c] = b_fgl[c * NOUT + j];
            }
#pragma unroll
            for (int k = 0; k < NCLS; ++k) {
                float ww = 0.f, cb = 0.f;
#pragma unroll
                for (int c = 0; c < COUT; ++c) {
                    const float wfc = W_fc[(c * NOUT + j) * NCLS + k];
                    ww += wf[c] * wfc;
                    cb += bf[c] * wfc;
                }
                Weff[j * NCLS + k] = ww;
                cpart[k] += cb;
            }
        }
#pragma unroll
        for (int k = 0; k < NCLS; ++k)
#pragma unroll
            for (int off = 32; off; off >>= 1)
                cpart[k] += __shfl_down(cpart[k], off);
        if ((t & 63) == 0) {
#pragma unroll
            for (int k = 0; k < NCLS; ++k) red[(t >> 6) * NCLS + k] = cpart[k];
        }
        __syncthreads();
        if (t < NCLS) {
            float s = b_fc[t];
#pragma unroll
            for (int w2 = 0; w2 < 4; ++w2) s += red[w2 * NCLS + t];
            cs[t] = s;
        }
        __syncthreads();
        for (int i = t; i < BATCH * NCLS; i += 256) out[i] = cs[i % NCLS];
    }
}

// ---------------------------------------------------------------------------
// 2: cursor[j] = exclusive prefix over bin totals (sum of 64 slabs)
// ---------------------------------------------------------------------------
__global__ __launch_bounds__(512) void prefix_kernel(
    const int* __restrict__ slab, int* __restrict__ cursor)
{
    __shared__ int sc[NOUT];
    const int t = threadIdx.x;
    int s = 0;
#pragma unroll
    for (int b = 0; b < H_BLOCKS; ++b) s += slab[b * NOUT + t];
    sc[t] = s;
    __syncthreads();
    for (int off = 1; off < NOUT; off <<= 1) {
        const int u = (t >= off) ? sc[t - off] : 0;
        __syncthreads();
        sc[t] += u;
        __syncthreads();
    }
    cursor[t] = sc[t] - s;
}

// ---------------------------------------------------------------------------
// 3: globally bin-sorted pixel list. key = (bin<<16)|p.
// ---------------------------------------------------------------------------
__global__ __launch_bounds__(256) void scatter_kernel(
    const int* __restrict__ seg, int* __restrict__ cursor,
    unsigned* __restrict__ key)
{
#pragma unroll
    for (int i = 0; i < 4; ++i) {
        const int p = blockIdx.x * 1024 + i * 256 + threadIdx.x;
        const int b = seg[p];
        const int r = atomicAdd(&cursor[b], 1);
        key[r] = ((unsigned)b << 16) | (unsigned)p;
    }
}

// ---------------------------------------------------------------------------
// 4: segment sum. Wave = 64 batch rows (lanes) x 64 sorted ranks.
// Scalar keys in SGPRs -> batched coalesced 128B loads -> uniform-branch
// register-run accumulation -> ~1.5 coalesced wave-wide atomic flushes.
// ---------------------------------------------------------------------------
__global__ __launch_bounds__(256) void segsum_kernel(
    const unsigned short* __restrict__ xT, const unsigned* __restrict__ key,
    float* __restrict__ hT)
{
    const int t = threadIdx.x, w = t >> 6, lane = t & 63;
    const int wid = blockIdx.x * 4 + w;      // 0..8191
    const int sg  = wid & 1023;              // rank segment (64 ranks)
    const int rg  = wid >> 10;               // row group (64 rows)
    const int nb  = rg * 64 + lane;

    const unsigned kv = key[sg * 64 + lane];

    int   prev = __builtin_amdgcn_readlane((int)kv, 0) >> 16;
    float acc  = 0.f;
#pragma unroll
    for (int c = 0; c < 2; ++c) {
        int   kb[32];
        float v[32];
#pragma unroll
        for (int i = 0; i < 32; ++i) {
            const int ki = __builtin_amdgcn_readlane((int)kv, c * 32 + i);
            kb[i] = ki >> 16;
            v[i]  = __uint_as_float(
                ((unsigned)xT[(size_t)(ki & 0xFFFF) * BATCH + nb]) << 16);
        }
#pragma unroll
        for (int i = 0; i < 32; ++i) {
            if (kb[i] != prev) {             // wave-uniform branch
                unsafeAtomicAdd(&hT[(size_t)prev * BATCH + nb], acc);
                prev = kb[i];
                acc  = 0.f;
            }
            acc += v[i];
        }
    }
    unsafeAtomicAdd(&hT[(size_t)prev * BATCH + nb], acc);
}

// ---------------------------------------------------------------------------
// 5: out[n,k] += sum_j hT[j][n] * Weff[j,k]   (out pre-init = cst)
// ---------------------------------------------------------------------------
__global__ __launch_bounds__(256) void out_kernel(
    const float* __restrict__ hT, const float* __restrict__ Weff,
    float* __restrict__ out)
{
    __shared__ float wl[64 * NCLS];
    const int t  = threadIdx.x;
    const int jc = blockIdx.x >> 1;
    for (int i = t; i < 64 * NCLS; i += 256) wl[i] = Weff[jc * 64 * NCLS + i];
    __syncthreads();

    const int n = (blockIdx.x & 1) * 256 + t;
    float acc[NCLS] = {};
#pragma unroll
    for (int jj = 0; jj < 64; ++jj) {
        const float hv = hT[(size_t)(jc * 64 + jj) * BATCH + n];
#pragma unroll
        for (int k = 0; k < NCLS; ++k) acc[k] += hv * wl[jj * NCLS + k];
    }
#pragma unroll
    for (int k = 0; k < NCLS; ++k)
        unsafeAtomicAdd(&out[n * NCLS + k], acc[k]);
}

// ---------------------------------------------------------------------------
extern "C" void kernel_launch(void* const* d_in, const int* in_sizes, int n_in,
                              void* d_out, int out_size, void* d_ws, size_t ws_size,
                              hipStream_t stream)
{
    const float* x     = (const float*)d_in[0];
    const float* W_fgl = (const float*)d_in[1];
    const float* b_fgl = (const float*)d_in[2];
    const float* W_fc  = (const float*)d_in[3];
    const float* b_fc  = (const float*)d_in[4];
    const int*   seg   = (const int*)d_in[5];
    float*       out   = (float*)d_out;

    // ws: hT 1MB | Weff 20KB | slab 128KB | cursor 2KB | key 256KB | xT 64MB
    char* ws = (char*)d_ws;
    float*          hT     = (float*)ws;                           // 1048576
    float*          Weff   = (float*)(ws + 1048576);               // 20480
    int*            slab   = (int*)(ws + 1069056);                 // 131072
    int*            cursor = (int*)(ws + 1200128);                 // 2048
    unsigned*       key    = (unsigned*)(ws + 1202176);            // 262144
    unsigned short* xT     = (unsigned short*)(ws + 1464320);      // 64MB

    fused1_kernel <<<dim3(TP_BLOCKS + H_BLOCKS + Z_BLOCKS + 1), 256, 0, stream>>>(
        x, seg, W_fgl, b_fgl, W_fc, b_fc, xT, slab, hT, Weff, out);

    prefix_kernel <<<dim3(1),    512, 0, stream>>>(slab, cursor);
    scatter_kernel<<<dim3(64),   256, 0, stream>>>(seg, cursor, key);
    segsum_kernel <<<dim3(2048), 256, 0, stream>>>(xT, key, hT);
    out_kernel    <<<dim3(16),   256, 0, stream>>>(hT, Weff, out);
}